// Round 4
// baseline (224.219 us; speedup 1.0000x reference)
//
#include <hip/hip_runtime.h>
#include <math.h>

#define S_LEN 2048
#define DIM   512
#define M_TOT 8192
#define NCH   (S_LEN / 64)

typedef __attribute__((ext_vector_type(8))) short bf16x8;
typedef __attribute__((ext_vector_type(4))) short bf16x4;
typedef __attribute__((ext_vector_type(4))) float f32x4;

#define MFMA(a, b, c) __builtin_amdgcn_mfma_f32_16x16x32_bf16((a), (b), (c), 0, 0, 0)

// Q pre-scale: 1/sqrt(64) * log2(e), so scores come out ready for exp2.
#define QSCALE 0.18033688f

__device__ __forceinline__ short f2b(float x) {            // round-half-up bf16
    union { float f; unsigned u; } v; v.f = x;
    return (short)((v.u + 0x8000u) >> 16);
}
__device__ __forceinline__ int pack2(float x, float y) {   // [bf16(x) | bf16(y)<<16]
    union { float f; unsigned u; } a, b; a.f = x; b.f = y;
    return __builtin_amdgcn_perm(b.u + 0x8000u, a.u + 0x8000u, 0x07060302u);
}

// ---------------------------------------------------------------------------
// Wt[n][k] bf16 = transpose+convert of W[k][n] f32. 64x64 tiles.
// ---------------------------------------------------------------------------
__global__ __launch_bounds__(256) void prep_wt(const float* Wq, const float* Wk, const float* Wo,
                                               short* Wtq, short* Wtk, short* Wto) {
    const int zi = blockIdx.z;
    const float* W = zi == 0 ? Wq : zi == 1 ? Wk : Wo;
    short*      Wt = zi == 0 ? Wtq : zi == 1 ? Wtk : Wto;
    __shared__ short Ts[64 * 72];
    const int t = threadIdx.x;
    const int k0 = blockIdx.x * 64, n0 = blockIdx.y * 64;
    #pragma unroll
    for (int it = 0; it < 4; ++it) {
        const int r = (t >> 4) + 16 * it;
        const int cq = t & 15;
        float4 v = *(const float4*)&W[(size_t)(k0 + r) * DIM + n0 + cq * 4];
        Ts[(4 * cq + 0) * 72 + r] = f2b(v.x);
        Ts[(4 * cq + 1) * 72 + r] = f2b(v.y);
        Ts[(4 * cq + 2) * 72 + r] = f2b(v.z);
        Ts[(4 * cq + 3) * 72 + r] = f2b(v.w);
    }
    __syncthreads();
    #pragma unroll
    for (int it = 0; it < 2; ++it) {
        const int n = (t >> 3) + 32 * it;
        const int sg = t & 7;
        *(bf16x8*)&Wt[(size_t)(n0 + n) * DIM + k0 + sg * 8] = *(const bf16x8*)&Ts[n * 72 + sg * 8];
    }
}

// ---------------------------------------------------------------------------
// Projection GEMMs (fused 3): 128x128 tile, BK=32, 4 waves. A is fp32,
// converted to bf16 in staging via packed perm. Q output pre-scaled by
// QSCALE. V output stored transposed per (b,h): Vt[(bh*64+hd)*2048 + s].
// ---------------------------------------------------------------------------
__global__ __launch_bounds__(256) void proj_gemm(const float* __restrict__ X,
                                                 const float* __restrict__ Y,
                                                 const float* __restrict__ Z,
                                                 const short* __restrict__ Wtq,
                                                 const short* __restrict__ Wtk,
                                                 const short* __restrict__ Wto,
                                                 short* __restrict__ Qb,
                                                 short* __restrict__ Kb,
                                                 short* __restrict__ Vt) {
    const int zi = blockIdx.z;
    const float* A  = zi == 0 ? X : zi == 1 ? Y : Z;
    const short* Bw = zi == 0 ? Wtq : zi == 1 ? Wtk : Wto;

    __shared__ short As[128 * 40];
    __shared__ short Bs[128 * 40];
    const int tid = threadIdx.x;
    const int w = tid >> 6, ln = tid & 63, l15 = ln & 15, quad = ln >> 4;
    const int m0 = blockIdx.x * 128, n0 = blockIdx.y * 128;
    const int wm = (w & 1) * 64, wn = (w >> 1) * 64;

    const int r0 = tid >> 2, r1 = r0 + 64;
    const int sg = tid & 3;
    const float* ap0 = A  + (size_t)(m0 + r0) * DIM + sg * 8;
    const float* ap1 = A  + (size_t)(m0 + r1) * DIM + sg * 8;
    const short* bp0 = Bw + (size_t)(n0 + r0) * DIM + sg * 8;
    const short* bp1 = Bw + (size_t)(n0 + r1) * DIM + sg * 8;

    float4 a0a = *(const float4*)ap0, a0b = *(const float4*)(ap0 + 4);
    float4 a1a = *(const float4*)ap1, a1b = *(const float4*)(ap1 + 4);
    bf16x8 b0 = *(const bf16x8*)bp0, b1 = *(const bf16x8*)bp1;

    f32x4 acc[4][4] = {};

    for (int k0 = 0; k0 < DIM; k0 += 32) {
        __syncthreads();
        {
            int4 p0 = { pack2(a0a.x, a0a.y), pack2(a0a.z, a0a.w),
                        pack2(a0b.x, a0b.y), pack2(a0b.z, a0b.w) };
            int4 p1 = { pack2(a1a.x, a1a.y), pack2(a1a.z, a1a.w),
                        pack2(a1b.x, a1b.y), pack2(a1b.z, a1b.w) };
            *(int4*)&As[r0 * 40 + sg * 8] = p0;
            *(int4*)&As[r1 * 40 + sg * 8] = p1;
            *(bf16x8*)&Bs[r0 * 40 + sg * 8] = b0;
            *(bf16x8*)&Bs[r1 * 40 + sg * 8] = b1;
        }
        __syncthreads();
        const int kn = (k0 + 32 < DIM) ? k0 + 32 : 0;
        a0a = *(const float4*)(ap0 + kn); a0b = *(const float4*)(ap0 + kn + 4);
        a1a = *(const float4*)(ap1 + kn); a1b = *(const float4*)(ap1 + kn + 4);
        b0 = *(const bf16x8*)(bp0 + kn); b1 = *(const bf16x8*)(bp1 + kn);

        bf16x8 af[4], bf[4];
        #pragma unroll
        for (int mf = 0; mf < 4; ++mf) af[mf] = *(const bf16x8*)&As[(wm + 16 * mf + l15) * 40 + quad * 8];
        #pragma unroll
        for (int nf = 0; nf < 4; ++nf) bf[nf] = *(const bf16x8*)&Bs[(wn + 16 * nf + l15) * 40 + quad * 8];
        #pragma unroll
        for (int mf = 0; mf < 4; ++mf)
            #pragma unroll
            for (int nf = 0; nf < 4; ++nf)
                acc[mf][nf] = MFMA(af[mf], bf[nf], acc[mf][nf]);
    }

    if (zi < 2) {
        short* C = zi == 0 ? Qb : Kb;
        const float scale = zi == 0 ? QSCALE : 1.0f;
        #pragma unroll
        for (int mf = 0; mf < 4; ++mf)
            #pragma unroll
            for (int nf = 0; nf < 4; ++nf)
                #pragma unroll
                for (int r = 0; r < 4; ++r)
                    C[(size_t)(m0 + wm + 16 * mf + 4 * quad + r) * DIM + n0 + wn + 16 * nf + l15] =
                        f2b(acc[mf][nf][r] * scale);
    } else {
        #pragma unroll
        for (int mf = 0; mf < 4; ++mf)
            #pragma unroll
            for (int nf = 0; nf < 4; ++nf) {
                const int col = n0 + wn + 16 * nf + l15;
                const int h = col >> 6, hd = col & 63;
                const int row0_ = m0 + wm + 16 * mf + 4 * quad;
                const int bb = row0_ >> 11, s0 = row0_ & 2047;
                int2 o = { pack2(acc[mf][nf][0], acc[mf][nf][1]),
                           pack2(acc[mf][nf][2], acc[mf][nf][3]) };
                *(int2*)&Vt[((size_t)((bb * 8 + h) * 64 + hd)) * S_LEN + s0] = o;
            }
    }
}

// ---------------------------------------------------------------------------
// Final GEMM: fp32 out = Ob_bf16 @ Wto^T. 128x128 tile.
// ---------------------------------------------------------------------------
__global__ __launch_bounds__(256) void out_gemm(const short* __restrict__ Ob,
                                                const short* __restrict__ Wto,
                                                float* __restrict__ Cout) {
    __shared__ short As[128 * 40];
    __shared__ short Bs[128 * 40];
    const int tid = threadIdx.x;
    const int w = tid >> 6, ln = tid & 63, l15 = ln & 15, quad = ln >> 4;
    const int m0 = blockIdx.x * 128, n0 = blockIdx.y * 128;
    const int wm = (w & 1) * 64, wn = (w >> 1) * 64;

    const int r0 = tid >> 2, r1 = r0 + 64;
    const int sg = tid & 3;
    const short* ap0 = Ob  + (size_t)(m0 + r0) * DIM + sg * 8;
    const short* ap1 = Ob  + (size_t)(m0 + r1) * DIM + sg * 8;
    const short* bp0 = Wto + (size_t)(n0 + r0) * DIM + sg * 8;
    const short* bp1 = Wto + (size_t)(n0 + r1) * DIM + sg * 8;

    bf16x8 a0 = *(const bf16x8*)ap0, a1 = *(const bf16x8*)ap1;
    bf16x8 b0 = *(const bf16x8*)bp0, b1 = *(const bf16x8*)bp1;

    f32x4 acc[4][4] = {};

    for (int k0 = 0; k0 < DIM; k0 += 32) {
        __syncthreads();
        *(bf16x8*)&As[r0 * 40 + sg * 8] = a0;
        *(bf16x8*)&As[r1 * 40 + sg * 8] = a1;
        *(bf16x8*)&Bs[r0 * 40 + sg * 8] = b0;
        *(bf16x8*)&Bs[r1 * 40 + sg * 8] = b1;
        __syncthreads();
        const int kn = (k0 + 32 < DIM) ? k0 + 32 : 0;
        a0 = *(const bf16x8*)(ap0 + kn); a1 = *(const bf16x8*)(ap1 + kn);
        b0 = *(const bf16x8*)(bp0 + kn); b1 = *(const bf16x8*)(bp1 + kn);

        bf16x8 af[4], bf[4];
        #pragma unroll
        for (int mf = 0; mf < 4; ++mf) af[mf] = *(const bf16x8*)&As[(wm + 16 * mf + l15) * 40 + quad * 8];
        #pragma unroll
        for (int nf = 0; nf < 4; ++nf) bf[nf] = *(const bf16x8*)&Bs[(wn + 16 * nf + l15) * 40 + quad * 8];
        #pragma unroll
        for (int mf = 0; mf < 4; ++mf)
            #pragma unroll
            for (int nf = 0; nf < 4; ++nf)
                acc[mf][nf] = MFMA(af[mf], bf[nf], acc[mf][nf]);
    }
    #pragma unroll
    for (int mf = 0; mf < 4; ++mf)
        #pragma unroll
        for (int nf = 0; nf < 4; ++nf)
            #pragma unroll
            for (int r = 0; r < 4; ++r)
                Cout[(size_t)(m0 + wm + 16 * mf + 4 * quad + r) * DIM + n0 + wn + 16 * nf + l15] =
                    acc[mf][nf][r];
}

// ---------------------------------------------------------------------------
// Attention: 512 threads = 8 waves x 16q = 128q per block, per (b,h).
// Double-buffered K/V LDS (1 barrier/chunk). Q pre-scaled so e = exp2(max(s,0)).
// bf16 pack via v_perm; softmax denominator via MFMA with all-ones B operand
// (row sums land in the same C-layout rows as oacc -> no cross-lane reduce).
// ---------------------------------------------------------------------------
__global__ __launch_bounds__(512) void attn_mfma(const short* __restrict__ Qb,
                                                 const short* __restrict__ Kb,
                                                 const short* __restrict__ Vtg,
                                                 short* __restrict__ Ob) {
    __shared__ short Ks[2][64 * 68];
    __shared__ short Vs[2][64 * 68];
    __shared__ short Es[8][16 * 68];

    const int tid = threadIdx.x;
    const int w = tid >> 6, ln = tid & 63, l15 = ln & 15, quad = ln >> 4;
    const int qt0 = blockIdx.x * 128;
    const int bh = blockIdx.y, b = bh >> 3, h = bh & 7;
    const size_t tokbase = (size_t)b * S_LEN;

    // resident Q fragments: wave w covers q rows [qt0+16w, qt0+16w+16)
    const size_t qrow = (tokbase + qt0 + 16 * w + l15) * DIM + h * 64 + 8 * quad;
    bf16x8 qf0 = *(const bf16x8*)&Qb[qrow];
    bf16x8 qf1 = *(const bf16x8*)&Qb[qrow + 32];

    const int srow = tid >> 3, ssg = tid & 7;    // srow 0..63
    const short* kbase = Kb  + (tokbase + srow) * DIM + h * 64 + ssg * 8;
    const short* vbase = Vtg + ((size_t)bh * 64 + srow) * S_LEN + ssg * 8;

    const bf16x8 ones = { 0x3F80, 0x3F80, 0x3F80, 0x3F80, 0x3F80, 0x3F80, 0x3F80, 0x3F80 };

    f32x4 oacc[4] = {};
    f32x4 dacc = {0.f, 0.f, 0.f, 0.f};

    bf16x8 kr, vr;
    // prologue: chunk0 -> buf0; prefetch chunk1 regs
    kr = *(const bf16x8*)kbase;
    vr = *(const bf16x8*)vbase;
    *(bf16x8*)&Ks[0][srow * 68 + ssg * 8] = kr;
    *(bf16x8*)&Vs[0][srow * 68 + ssg * 8] = vr;
    kr = *(const bf16x8*)(kbase + (size_t)64 * DIM);
    vr = *(const bf16x8*)(vbase + 64);
    __syncthreads();

    for (int kc = 0; kc < NCH; ++kc) {
        const int cur = kc & 1;
        if (kc + 1 < NCH) {
            *(bf16x8*)&Ks[cur ^ 1][srow * 68 + ssg * 8] = kr;
            *(bf16x8*)&Vs[cur ^ 1][srow * 68 + ssg * 8] = vr;
        }
        if (kc + 2 < NCH) {
            kr = *(const bf16x8*)(kbase + (size_t)(kc + 2) * 64 * DIM);
            vr = *(const bf16x8*)(vbase + (size_t)(kc + 2) * 64);
        }

        // ---- phase 1: S^T[key][q] = K * Q^T  (rows=key, col=q=l15) ----
        f32x4 sacc[4];
        #pragma unroll
        for (int mf = 0; mf < 4; ++mf) {
            bf16x8 ka = *(const bf16x8*)&Ks[cur][(16 * mf + l15) * 68 + 8 * quad];
            bf16x8 kb2 = *(const bf16x8*)&Ks[cur][(16 * mf + l15) * 68 + 32 + 8 * quad];
            f32x4 s = {0.f, 0.f, 0.f, 0.f};
            s = MFMA(ka, qf0, s);
            s = MFMA(kb2, qf1, s);
            sacc[mf] = s;
        }

        // ---- e = exp2(max(s,0)) -> Es (per-wave rows, packed writes) ----
        short* Esw = &Es[w][0];
        #pragma unroll
        for (int mf = 0; mf < 4; ++mf) {
            float e0 = __builtin_amdgcn_exp2f(fmaxf(sacc[mf][0], 0.f));
            float e1 = __builtin_amdgcn_exp2f(fmaxf(sacc[mf][1], 0.f));
            float e2 = __builtin_amdgcn_exp2f(fmaxf(sacc[mf][2], 0.f));
            float e3 = __builtin_amdgcn_exp2f(fmaxf(sacc[mf][3], 0.f));
            int2 p = { pack2(e0, e1), pack2(e2, e3) };
            *(int2*)&Esw[l15 * 68 + 16 * mf + 4 * quad] = p;
        }

        // ---- phase 2: O[q][hd] += E * V ; denom += E * ones ----
        bf16x8 e0 = *(const bf16x8*)&Esw[l15 * 68 + 8 * quad];
        bf16x8 e1 = *(const bf16x8*)&Esw[l15 * 68 + 32 + 8 * quad];
        dacc = MFMA(e0, ones, dacc);
        dacc = MFMA(e1, ones, dacc);
        #pragma unroll
        for (int nf2 = 0; nf2 < 4; ++nf2) {
            bf16x8 vf0 = *(const bf16x8*)&Vs[cur][(16 * nf2 + l15) * 68 + 8 * quad];
            bf16x8 vf1 = *(const bf16x8*)&Vs[cur][(16 * nf2 + l15) * 68 + 32 + 8 * quad];
            oacc[nf2] = MFMA(e0, vf0, oacc[nf2]);
            oacc[nf2] = MFMA(e1, vf1, oacc[nf2]);
        }
        __syncthreads();
    }

    // ---- normalize + store: dacc rows match oacc rows (4*quad + r) ----
    #pragma unroll
    for (int r = 0; r < 4; ++r) {
        const float di = __builtin_amdgcn_rcpf(dacc[r]);
        const size_t rowaddr = (tokbase + qt0 + 16 * w + 4 * quad + r) * DIM + h * 64;
        #pragma unroll
        for (int nf2 = 0; nf2 < 4; ++nf2)
            Ob[rowaddr + 16 * nf2 + l15] = f2b(oacc[nf2][r] * di);
    }
}

// ---------------------------------------------------------------------------
extern "C" void kernel_launch(void* const* d_in, const int* in_sizes, int n_in,
                              void* d_out, int out_size, void* d_ws, size_t ws_size,
                              hipStream_t stream) {
    const float* X  = (const float*)d_in[0];
    const float* Y  = (const float*)d_in[1];
    const float* Z  = (const float*)d_in[2];
    const float* Wq = (const float*)d_in[3];
    const float* Wk = (const float*)d_in[4];
    // d_in[5] = Wv dead in reference forward
    const float* Wo = (const float*)d_in[6];

    char* p = (char*)d_ws;
    const size_t MD = (size_t)M_TOT * DIM;
    short* Qb  = (short*)p; p += MD * 2;
    short* Kb  = (short*)p; p += MD * 2;
    short* Vt  = (short*)p; p += MD * 2;
    short* Ob  = (short*)p; p += MD * 2;
    short* Wtq = (short*)p; p += (size_t)DIM * DIM * 2;
    short* Wtk = (short*)p; p += (size_t)DIM * DIM * 2;
    short* Wto = (short*)p; p += (size_t)DIM * DIM * 2;

    prep_wt<<<dim3(8, 8, 3), 256, 0, stream>>>(Wq, Wk, Wo, Wtq, Wtk, Wto);
    proj_gemm<<<dim3(64, 4, 3), 256, 0, stream>>>(X, Y, Z, Wtq, Wtk, Wto, Qb, Kb, Vt);
    attn_mfma<<<dim3(16, 32), 512, 0, stream>>>(Qb, Kb, Vt, Ob);
    out_gemm<<<dim3(64, 4), 256, 0, stream>>>(Ob, Wto, (float*)d_out);
}

// Round 5
// 217.487 us; speedup vs baseline: 1.0310x; 1.0310x over previous
//
#include <hip/hip_runtime.h>
#include <math.h>

#define S_LEN 2048
#define DIM   512
#define M_TOT 8192
#define NCH   (S_LEN / 64)

typedef __attribute__((ext_vector_type(8))) short bf16x8;
typedef __attribute__((ext_vector_type(4))) short bf16x4;
typedef __attribute__((ext_vector_type(4))) float f32x4;

#define MFMA(a, b, c) __builtin_amdgcn_mfma_f32_16x16x32_bf16((a), (b), (c), 0, 0, 0)

// Q pre-scale: 1/sqrt(64) * log2(e), so scores come out ready for exp2.
#define QSCALE 0.18033688f

__device__ __forceinline__ short f2b(float x) {            // round-half-up bf16
    union { float f; unsigned u; } v; v.f = x;
    return (short)((v.u + 0x8000u) >> 16);
}
__device__ __forceinline__ int pack2(float x, float y) {   // [bf16(x) | bf16(y)<<16]
    union { float f; unsigned u; } a, b; a.f = x; b.f = y;
    return __builtin_amdgcn_perm(b.u + 0x8000u, a.u + 0x8000u, 0x07060302u);
}

// ---------------------------------------------------------------------------
// fp32 -> bf16 bulk convert (X,Y,Z). One thread per 8 floats.
// ---------------------------------------------------------------------------
__global__ __launch_bounds__(256) void cvt_bf16(const float* __restrict__ X,
                                                const float* __restrict__ Y,
                                                const float* __restrict__ Z,
                                                short* __restrict__ Xb,
                                                short* __restrict__ Yb,
                                                short* __restrict__ Zb) {
    const int zi = blockIdx.y;
    const float* A = zi == 0 ? X : zi == 1 ? Y : Z;
    short* O = zi == 0 ? Xb : zi == 1 ? Yb : Zb;
    const size_t i = (size_t)blockIdx.x * 256 + threadIdx.x;
    float4 a = ((const float4*)A)[2 * i];
    float4 b = ((const float4*)A)[2 * i + 1];
    int4 o = { pack2(a.x, a.y), pack2(a.z, a.w), pack2(b.x, b.y), pack2(b.z, b.w) };
    *(int4*)&O[i * 8] = o;
}

// ---------------------------------------------------------------------------
// Wt[n][k] bf16 = transpose+convert of W[k][n] f32. 64x64 tiles.
// ---------------------------------------------------------------------------
__global__ __launch_bounds__(256) void prep_wt(const float* Wq, const float* Wk, const float* Wo,
                                               short* Wtq, short* Wtk, short* Wto) {
    const int zi = blockIdx.z;
    const float* W = zi == 0 ? Wq : zi == 1 ? Wk : Wo;
    short*      Wt = zi == 0 ? Wtq : zi == 1 ? Wtk : Wto;
    __shared__ short Ts[64 * 72];
    const int t = threadIdx.x;
    const int k0 = blockIdx.x * 64, n0 = blockIdx.y * 64;
    #pragma unroll
    for (int it = 0; it < 4; ++it) {
        const int r = (t >> 4) + 16 * it;
        const int cq = t & 15;
        float4 v = *(const float4*)&W[(size_t)(k0 + r) * DIM + n0 + cq * 4];
        Ts[(4 * cq + 0) * 72 + r] = f2b(v.x);
        Ts[(4 * cq + 1) * 72 + r] = f2b(v.y);
        Ts[(4 * cq + 2) * 72 + r] = f2b(v.z);
        Ts[(4 * cq + 3) * 72 + r] = f2b(v.w);
    }
    __syncthreads();
    #pragma unroll
    for (int it = 0; it < 2; ++it) {
        const int n = (t >> 3) + 32 * it;
        const int sg = t & 7;
        *(bf16x8*)&Wt[(size_t)(n0 + n) * DIM + k0 + sg * 8] = *(const bf16x8*)&Ts[n * 72 + sg * 8];
    }
}

// ---------------------------------------------------------------------------
// Projection GEMMs (fused 3): 128x128 tile, BK=32, 4 waves, pure bf16.
// Q output pre-scaled by QSCALE. V stored transposed per (b,h):
// Vt[(bh*64+hd)*2048 + s].
// ---------------------------------------------------------------------------
__global__ __launch_bounds__(256) void proj_gemm(const short* __restrict__ Xb,
                                                 const short* __restrict__ Yb,
                                                 const short* __restrict__ Zb,
                                                 const short* __restrict__ Wtq,
                                                 const short* __restrict__ Wtk,
                                                 const short* __restrict__ Wto,
                                                 short* __restrict__ Qb,
                                                 short* __restrict__ Kb,
                                                 short* __restrict__ Vt) {
    const int zi = blockIdx.z;
    const short* A  = zi == 0 ? Xb : zi == 1 ? Yb : Zb;
    const short* Bw = zi == 0 ? Wtq : zi == 1 ? Wtk : Wto;

    __shared__ short As[128 * 40];
    __shared__ short Bs[128 * 40];
    const int tid = threadIdx.x;
    const int w = tid >> 6, ln = tid & 63, l15 = ln & 15, quad = ln >> 4;
    const int m0 = blockIdx.x * 128, n0 = blockIdx.y * 128;
    const int wm = (w & 1) * 64, wn = (w >> 1) * 64;

    const int r0 = tid >> 2, r1 = r0 + 64;
    const int sg = tid & 3;
    const short* ap0 = A  + (size_t)(m0 + r0) * DIM + sg * 8;
    const short* ap1 = A  + (size_t)(m0 + r1) * DIM + sg * 8;
    const short* bp0 = Bw + (size_t)(n0 + r0) * DIM + sg * 8;
    const short* bp1 = Bw + (size_t)(n0 + r1) * DIM + sg * 8;

    bf16x8 a0 = *(const bf16x8*)ap0, a1 = *(const bf16x8*)ap1;
    bf16x8 b0 = *(const bf16x8*)bp0, b1 = *(const bf16x8*)bp1;

    f32x4 acc[4][4] = {};

    for (int k0 = 0; k0 < DIM; k0 += 32) {
        __syncthreads();
        *(bf16x8*)&As[r0 * 40 + sg * 8] = a0;
        *(bf16x8*)&As[r1 * 40 + sg * 8] = a1;
        *(bf16x8*)&Bs[r0 * 40 + sg * 8] = b0;
        *(bf16x8*)&Bs[r1 * 40 + sg * 8] = b1;
        __syncthreads();
        const int kn = (k0 + 32 < DIM) ? k0 + 32 : 0;
        a0 = *(const bf16x8*)(ap0 + kn); a1 = *(const bf16x8*)(ap1 + kn);
        b0 = *(const bf16x8*)(bp0 + kn); b1 = *(const bf16x8*)(bp1 + kn);

        bf16x8 af[4], bf[4];
        #pragma unroll
        for (int mf = 0; mf < 4; ++mf) af[mf] = *(const bf16x8*)&As[(wm + 16 * mf + l15) * 40 + quad * 8];
        #pragma unroll
        for (int nf = 0; nf < 4; ++nf) bf[nf] = *(const bf16x8*)&Bs[(wn + 16 * nf + l15) * 40 + quad * 8];
        #pragma unroll
        for (int mf = 0; mf < 4; ++mf)
            #pragma unroll
            for (int nf = 0; nf < 4; ++nf)
                acc[mf][nf] = MFMA(af[mf], bf[nf], acc[mf][nf]);
    }

    if (zi < 2) {
        short* C = zi == 0 ? Qb : Kb;
        const float scale = zi == 0 ? QSCALE : 1.0f;
        #pragma unroll
        for (int mf = 0; mf < 4; ++mf)
            #pragma unroll
            for (int nf = 0; nf < 4; ++nf) {
                int2 o = { pack2(acc[mf][nf][0] * scale, acc[mf][nf][1] * scale),
                           pack2(acc[mf][nf][2] * scale, acc[mf][nf][3] * scale) };
                // rows are 4*quad+r consecutive -> but C layout is row-major; store per r
                C[(size_t)(m0 + wm + 16 * mf + 4 * quad + 0) * DIM + n0 + wn + 16 * nf + l15] = (short)(o.x & 0xFFFF);
                C[(size_t)(m0 + wm + 16 * mf + 4 * quad + 1) * DIM + n0 + wn + 16 * nf + l15] = (short)(o.x >> 16);
                C[(size_t)(m0 + wm + 16 * mf + 4 * quad + 2) * DIM + n0 + wn + 16 * nf + l15] = (short)(o.y & 0xFFFF);
                C[(size_t)(m0 + wm + 16 * mf + 4 * quad + 3) * DIM + n0 + wn + 16 * nf + l15] = (short)(o.y >> 16);
            }
    } else {
        #pragma unroll
        for (int mf = 0; mf < 4; ++mf)
            #pragma unroll
            for (int nf = 0; nf < 4; ++nf) {
                const int col = n0 + wn + 16 * nf + l15;
                const int h = col >> 6, hd = col & 63;
                const int row0_ = m0 + wm + 16 * mf + 4 * quad;
                const int bb = row0_ >> 11, s0 = row0_ & 2047;
                int2 o = { pack2(acc[mf][nf][0], acc[mf][nf][1]),
                           pack2(acc[mf][nf][2], acc[mf][nf][3]) };
                *(int2*)&Vt[((size_t)((bb * 8 + h) * 64 + hd)) * S_LEN + s0] = o;
            }
    }
}

// ---------------------------------------------------------------------------
// Final GEMM: fp32 out = Ob_bf16 @ Wto^T. 128x128 tile.
// ---------------------------------------------------------------------------
__global__ __launch_bounds__(256) void out_gemm(const short* __restrict__ Ob,
                                                const short* __restrict__ Wto,
                                                float* __restrict__ Cout) {
    __shared__ short As[128 * 40];
    __shared__ short Bs[128 * 40];
    const int tid = threadIdx.x;
    const int w = tid >> 6, ln = tid & 63, l15 = ln & 15, quad = ln >> 4;
    const int m0 = blockIdx.x * 128, n0 = blockIdx.y * 128;
    const int wm = (w & 1) * 64, wn = (w >> 1) * 64;

    const int r0 = tid >> 2, r1 = r0 + 64;
    const int sg = tid & 3;
    const short* ap0 = Ob  + (size_t)(m0 + r0) * DIM + sg * 8;
    const short* ap1 = Ob  + (size_t)(m0 + r1) * DIM + sg * 8;
    const short* bp0 = Wto + (size_t)(n0 + r0) * DIM + sg * 8;
    const short* bp1 = Wto + (size_t)(n0 + r1) * DIM + sg * 8;

    bf16x8 a0 = *(const bf16x8*)ap0, a1 = *(const bf16x8*)ap1;
    bf16x8 b0 = *(const bf16x8*)bp0, b1 = *(const bf16x8*)bp1;

    f32x4 acc[4][4] = {};

    for (int k0 = 0; k0 < DIM; k0 += 32) {
        __syncthreads();
        *(bf16x8*)&As[r0 * 40 + sg * 8] = a0;
        *(bf16x8*)&As[r1 * 40 + sg * 8] = a1;
        *(bf16x8*)&Bs[r0 * 40 + sg * 8] = b0;
        *(bf16x8*)&Bs[r1 * 40 + sg * 8] = b1;
        __syncthreads();
        const int kn = (k0 + 32 < DIM) ? k0 + 32 : 0;
        a0 = *(const bf16x8*)(ap0 + kn); a1 = *(const bf16x8*)(ap1 + kn);
        b0 = *(const bf16x8*)(bp0 + kn); b1 = *(const bf16x8*)(bp1 + kn);

        bf16x8 af[4], bf[4];
        #pragma unroll
        for (int mf = 0; mf < 4; ++mf) af[mf] = *(const bf16x8*)&As[(wm + 16 * mf + l15) * 40 + quad * 8];
        #pragma unroll
        for (int nf = 0; nf < 4; ++nf) bf[nf] = *(const bf16x8*)&Bs[(wn + 16 * nf + l15) * 40 + quad * 8];
        #pragma unroll
        for (int mf = 0; mf < 4; ++mf)
            #pragma unroll
            for (int nf = 0; nf < 4; ++nf)
                acc[mf][nf] = MFMA(af[mf], bf[nf], acc[mf][nf]);
    }
    #pragma unroll
    for (int mf = 0; mf < 4; ++mf)
        #pragma unroll
        for (int nf = 0; nf < 4; ++nf)
            #pragma unroll
            for (int r = 0; r < 4; ++r)
                Cout[(size_t)(m0 + wm + 16 * mf + 4 * quad + r) * DIM + n0 + wn + 16 * nf + l15] =
                    acc[mf][nf][r];
}

// ---------------------------------------------------------------------------
// Attention: 512 threads = 8 waves x 32q = 256q per block, per (b,h).
// Grid (8, 32) = 256 blocks. LDS-read-optimized: per wave-chunk 20 b128 reads
// (Ks 8 + Vs 8 + Es 4, V-frags shared across both q-frags) for 36 MFMAs.
// Double-buffered K/V staging, exp2(max(s,0)) with pre-scaled Q, packed bf16
// via v_perm, denominator via MFMA-with-ones (no cross-lane reduce).
// ---------------------------------------------------------------------------
__global__ __launch_bounds__(512, 2) void attn_mfma(const short* __restrict__ Qb,
                                                    const short* __restrict__ Kb,
                                                    const short* __restrict__ Vtg,
                                                    short* __restrict__ Ob) {
    __shared__ short Ks[2][64 * 68];
    __shared__ short Vs[2][64 * 68];
    __shared__ short Es[8][32 * 68];

    const int tid = threadIdx.x;
    const int w = tid >> 6, ln = tid & 63, l15 = ln & 15, quad = ln >> 4;
    const int qt0 = blockIdx.x * 256;
    const int bh = blockIdx.y, b = bh >> 3, h = bh & 7;
    const size_t tokbase = (size_t)b * S_LEN;

    // resident Q fragments: wave w covers q rows [qt0+32w, qt0+32w+32)
    bf16x8 qf[2][2];
    #pragma unroll
    for (int nf = 0; nf < 2; ++nf)
        #pragma unroll
        for (int ks = 0; ks < 2; ++ks)
            qf[nf][ks] = *(const bf16x8*)&Qb[(tokbase + qt0 + 32 * w + 16 * nf + l15) * DIM +
                                             h * 64 + 32 * ks + 8 * quad];

    const int srow = tid >> 3, ssg = tid & 7;    // srow 0..63
    const short* kbase = Kb  + (tokbase + srow) * DIM + h * 64 + ssg * 8;
    const short* vbase = Vtg + ((size_t)bh * 64 + srow) * S_LEN + ssg * 8;

    const bf16x8 ones = { 0x3F80, 0x3F80, 0x3F80, 0x3F80, 0x3F80, 0x3F80, 0x3F80, 0x3F80 };

    f32x4 oacc[2][4] = {};
    f32x4 dacc[2] = {};

    bf16x8 kr, vr;
    // prologue: chunk0 -> buf0; prefetch chunk1 regs
    kr = *(const bf16x8*)kbase;
    vr = *(const bf16x8*)vbase;
    *(bf16x8*)&Ks[0][srow * 68 + ssg * 8] = kr;
    *(bf16x8*)&Vs[0][srow * 68 + ssg * 8] = vr;
    kr = *(const bf16x8*)(kbase + (size_t)64 * DIM);
    vr = *(const bf16x8*)(vbase + 64);
    __syncthreads();

    for (int kc = 0; kc < NCH; ++kc) {
        const int cur = kc & 1;
        if (kc + 1 < NCH) {
            *(bf16x8*)&Ks[cur ^ 1][srow * 68 + ssg * 8] = kr;
            *(bf16x8*)&Vs[cur ^ 1][srow * 68 + ssg * 8] = vr;
        }
        if (kc + 2 < NCH) {
            kr = *(const bf16x8*)(kbase + (size_t)(kc + 2) * 64 * DIM);
            vr = *(const bf16x8*)(vbase + (size_t)(kc + 2) * 64);
        }

        // ---- phase 1: S^T[key][q] = K * Q^T (rows=key, cols=q) ----
        f32x4 sacc[4][2];
        #pragma unroll
        for (int mf = 0; mf < 4; ++mf) {
            bf16x8 ka  = *(const bf16x8*)&Ks[cur][(16 * mf + l15) * 68 + 8 * quad];
            bf16x8 kb2 = *(const bf16x8*)&Ks[cur][(16 * mf + l15) * 68 + 32 + 8 * quad];
            #pragma unroll
            for (int nf = 0; nf < 2; ++nf) {
                f32x4 s = {0.f, 0.f, 0.f, 0.f};
                s = MFMA(ka, qf[nf][0], s);
                s = MFMA(kb2, qf[nf][1], s);
                sacc[mf][nf] = s;
            }
        }

        // ---- e = exp2(max(s,0)) -> Es (per-wave rows, packed b64 writes) ----
        short* Esw = &Es[w][0];
        #pragma unroll
        for (int mf = 0; mf < 4; ++mf)
            #pragma unroll
            for (int nf = 0; nf < 2; ++nf) {
                float e0 = __builtin_amdgcn_exp2f(fmaxf(sacc[mf][nf][0], 0.f));
                float e1 = __builtin_amdgcn_exp2f(fmaxf(sacc[mf][nf][1], 0.f));
                float e2 = __builtin_amdgcn_exp2f(fmaxf(sacc[mf][nf][2], 0.f));
                float e3 = __builtin_amdgcn_exp2f(fmaxf(sacc[mf][nf][3], 0.f));
                int2 p = { pack2(e0, e1), pack2(e2, e3) };
                *(int2*)&Esw[(16 * nf + l15) * 68 + 16 * mf + 4 * quad] = p;
            }

        // ---- phase 2: O[q][hd] += E * V ; denom += E * ones ----
        bf16x8 e[2][2];
        #pragma unroll
        for (int nf = 0; nf < 2; ++nf) {
            e[nf][0] = *(const bf16x8*)&Esw[(16 * nf + l15) * 68 + 8 * quad];
            e[nf][1] = *(const bf16x8*)&Esw[(16 * nf + l15) * 68 + 32 + 8 * quad];
            dacc[nf] = MFMA(e[nf][0], ones, dacc[nf]);
            dacc[nf] = MFMA(e[nf][1], ones, dacc[nf]);
        }
        #pragma unroll
        for (int nf2 = 0; nf2 < 4; ++nf2) {
            bf16x8 vf0 = *(const bf16x8*)&Vs[cur][(16 * nf2 + l15) * 68 + 8 * quad];
            bf16x8 vf1 = *(const bf16x8*)&Vs[cur][(16 * nf2 + l15) * 68 + 32 + 8 * quad];
            #pragma unroll
            for (int nf = 0; nf < 2; ++nf) {
                oacc[nf][nf2] = MFMA(e[nf][0], vf0, oacc[nf][nf2]);
                oacc[nf][nf2] = MFMA(e[nf][1], vf1, oacc[nf][nf2]);
            }
        }
        __syncthreads();
    }

    // ---- normalize + store: dacc rows match oacc rows (4*quad + r) ----
    #pragma unroll
    for (int nf = 0; nf < 2; ++nf)
        #pragma unroll
        for (int r = 0; r < 4; ++r) {
            const float di = __builtin_amdgcn_rcpf(dacc[nf][r]);
            const size_t rowaddr = (tokbase + qt0 + 32 * w + 16 * nf + 4 * quad + r) * DIM + h * 64;
            #pragma unroll
            for (int nf2 = 0; nf2 < 4; ++nf2)
                Ob[rowaddr + 16 * nf2 + l15] = f2b(oacc[nf][nf2][r] * di);
        }
}

// ---------------------------------------------------------------------------
extern "C" void kernel_launch(void* const* d_in, const int* in_sizes, int n_in,
                              void* d_out, int out_size, void* d_ws, size_t ws_size,
                              hipStream_t stream) {
    const float* X  = (const float*)d_in[0];
    const float* Y  = (const float*)d_in[1];
    const float* Z  = (const float*)d_in[2];
    const float* Wq = (const float*)d_in[3];
    const float* Wk = (const float*)d_in[4];
    // d_in[5] = Wv dead in reference forward
    const float* Wo = (const float*)d_in[6];

    char* p = (char*)d_ws;
    const size_t MD = (size_t)M_TOT * DIM;
    short* Qb  = (short*)p; p += MD * 2;
    short* Kb  = (short*)p; p += MD * 2;
    short* Vt  = (short*)p; p += MD * 2;
    short* Ob  = (short*)p; p += MD * 2;
    short* Xb  = (short*)p; p += MD * 2;
    short* Yb  = (short*)p; p += MD * 2;
    short* Zb  = (short*)p; p += MD * 2;
    short* Wtq = (short*)p; p += (size_t)DIM * DIM * 2;
    short* Wtk = (short*)p; p += (size_t)DIM * DIM * 2;
    short* Wto = (short*)p; p += (size_t)DIM * DIM * 2;

    cvt_bf16<<<dim3(M_TOT * DIM / 8 / 256, 3), 256, 0, stream>>>(X, Y, Z, Xb, Yb, Zb);
    prep_wt<<<dim3(8, 8, 3), 256, 0, stream>>>(Wq, Wk, Wo, Wtq, Wtk, Wto);
    proj_gemm<<<dim3(64, 4, 3), 256, 0, stream>>>(Xb, Yb, Zb, Wtq, Wtk, Wto, Qb, Kb, Vt);
    attn_mfma<<<dim3(8, 32), 512, 0, stream>>>(Qb, Kb, Vt, Ob);
    out_gemm<<<dim3(64, 4), 256, 0, stream>>>(Ob, Wto, (float*)d_out);
}